// Round 3
// baseline (555.106 us; speedup 1.0000x reference)
//
#include <hip/hip_runtime.h>

typedef unsigned short u16;
typedef unsigned int   u32;
typedef __attribute__((ext_vector_type(4))) float  f32x4;
typedef __attribute__((ext_vector_type(8))) short  s16x8;
typedef __attribute__((ext_vector_type(8))) __bf16 bf16x8;
typedef __attribute__((ext_vector_type(2))) u32    u32x2;

#define DEV __device__ __forceinline__
#define SCALE_Q 0.1889822365046136f   // 28^-0.5

DEV float bf2f(u16 u){ u32 x = ((u32)u)<<16; float f; __builtin_memcpy(&f,&x,4); return f; }
DEV u16   f2bf(float f){ u32 x; __builtin_memcpy(&x,&f,4); return (u16)((x + 0x7fffu + ((x>>16)&1u))>>16); }

// 8 consecutive f32 -> 8 bf16 (RNE via __bf16 cast; compiler emits cvt_pk)
DEV s16x8 cvt8(const float* __restrict__ src){
  f32x4 f0 = *(const f32x4*)src, f1 = *(const f32x4*)(src+4);
  bf16x8 b;
  b[0]=(__bf16)f0[0]; b[1]=(__bf16)f0[1]; b[2]=(__bf16)f0[2]; b[3]=(__bf16)f0[3];
  b[4]=(__bf16)f1[0]; b[5]=(__bf16)f1[1]; b[6]=(__bf16)f1[2]; b[7]=(__bf16)f1[3];
  return __builtin_bit_cast(s16x8, b);
}

// load 28 bf16 (8-byte aligned) -> 28 floats, scaled
DEV void ld28(const u16* __restrict__ p, float* dst, float scale){
#pragma unroll
  for (int j=0;j<7;j++){
    u32x2 w = *(const u32x2*)(p + j*4);
    dst[j*4+0] = bf2f((u16)(w[0]&0xffffu))*scale;
    dst[j*4+1] = bf2f((u16)(w[0]>>16))*scale;
    dst[j*4+2] = bf2f((u16)(w[1]&0xffffu))*scale;
    dst[j*4+3] = bf2f((u16)(w[1]>>16))*scale;
  }
}

// ---------------------------------------------------------------------------
// Weight packing (f32 in -> bf16 out):
//  WqkvT [672][224] : rows 0..223 = Wq col n ; 224..447 = Wkv col n (k) ; 448..671 = Wkv col 224+n (v)
//  WoutT [448][224]
//  convW [4][224][2016] : [conv][co][tap*224+ci], kd=1 slice only (D=1 w/ pad -> only middle plane)
// total elems = 150528 + 100352 + 1806336 = 2057216 = 8036*256
// ---------------------------------------------------------------------------
__global__ void pack_k(const float* __restrict__ Wq, const float* __restrict__ Wkv,
                       const float* __restrict__ Wout,
                       const float* __restrict__ wr, const float* __restrict__ w1,
                       const float* __restrict__ w2, const float* __restrict__ w3,
                       u16* __restrict__ WqkvT, u16* __restrict__ WoutT,
                       u16* __restrict__ convW)
{
  int idx = blockIdx.x*256 + threadIdx.x;
  if (idx < 150528) {
    int nn = idx/224, k = idx - nn*224;
    float v;
    if (nn < 224)      v = Wq [k*224 + nn];
    else if (nn < 448) v = Wkv[k*448 + (nn-224)];
    else               v = Wkv[k*448 + (nn-448) + 224];
    WqkvT[idx] = f2bf(v);
  } else if (idx < 250880) {
    int j = idx - 150528;
    int nn = j/224, k = j - nn*224;
    WoutT[j] = f2bf(Wout[k*448 + nn]);
  } else {
    int j = idx - 250880;
    int cv = j/451584, rem = j - cv*451584;
    int co = rem/2016, kk = rem - co*2016;
    int tap = kk/224, ci = kk - tap*224;
    const float* w = (cv==0)?wr:(cv==1)?w1:(cv==2)?w2:w3;
    convW[j] = f2bf(w[(co*224 + ci)*27 + 9 + tap]);  // kd=1 -> +9
  }
}

// ---------------------------------------------------------------------------
// GEMM template: C[65536 x N] = A[65536 x K] * Bt^T  (Bt stored [N][K] bf16)
// BM=128, BN=224, BK=32, 512 threads (8 waves: 4 along M x 2 along N),
// wave tile 32x112 -> 2x7 frags of 16x16, mfma_f32_16x16x32_bf16.
// MFMA layouts (learn_hip m89): A/B operand: lane l holds stored-row (l&15),
// k = 8*(l>>4)+i ; D: row=(l>>4)*4+reg, col=l&15.
// ---------------------------------------------------------------------------
enum { M_QKV=0, M_CX2=1, M_CBF=2, M_C3=3, M_OUT=4 };

template<int MODE>
__global__ __launch_bounds__(512,2) void gemm_k(
    const void* __restrict__ Av, const u16* __restrict__ Bt,
    const float* __restrict__ bias, const u16* __restrict__ resid,
    void* __restrict__ Dv)
{
  constexpr bool CONV = (MODE==M_CX2 || MODE==M_CBF || MODE==M_C3);
  constexpr bool AF32 = (MODE==M_QKV || MODE==M_CX2);   // A = x (float32)
  constexpr int KTOT = CONV ? 2016 : 224;   // conv: 9 taps x 224
  constexpr int KS   = KTOT/32;
  constexpr int ASTR = AF32 ? 448 : 224;
  constexpr int AOFF = (MODE==M_CX2) ? 224 : 0;

  __shared__ __align__(16) u16 Als[128][40];   // pad 32->40: 2-way banks only
  __shared__ __align__(16) u16 Bls[224][40];

  const int t  = threadIdx.x;
  const int bm = blockIdx.x, nb = blockIdx.y;
  const int lane = t&63, lr = lane&15, lg = lane>>4;
  const int w = t>>6, wm = w>>1, wn = w&1;
  const int ar = t>>2, aq = t&3;
  const int p  = bm*128 + ar;
  const int pb = p>>10, py = (p>>5)&31, px = p&31;

  f32x4 acc[2][7];
  { f32x4 zf = {0.f,0.f,0.f,0.f};
#pragma unroll
    for (int i=0;i<2;i++)
#pragma unroll
      for (int j=0;j<7;j++) acc[i][j] = zf; }

  const s16x8 zv = {0,0,0,0,0,0,0,0};

  for (int ks=0; ks<KS; ++ks) {
    // ---- A chunk (reg-staged: border masking + f32->bf16 convert) ----
    s16x8 av;
    if constexpr (CONV) {
      const int tap = ks/7, kc = ks - tap*7;
      const int dy = tap/3 - 1, dx = tap - (tap/3)*3 - 1;
      const int yy = py+dy, xx = px+dx;
      const bool ok = (yy>=0) & (yy<32) & (xx>=0) & (xx<32);
      const int yyc = yy<0?0:(yy>31?31:yy);        // clamp: loads always in-bounds
      const int xxc = xx<0?0:(xx>31?31:xx);
      const int off = ((pb*32+yyc)*32+xxc)*ASTR + AOFF + kc*32 + aq*8;
      s16x8 val;
      if constexpr (AF32) val = cvt8((const float*)Av + off);
      else                val = *(const s16x8*)((const u16*)Av + off);
      av = ok ? val : zv;
    } else {
      const int off = p*ASTR + ks*32 + aq*8;
      if constexpr (AF32) av = cvt8((const float*)Av + off);
      else                av = *(const s16x8*)((const u16*)Av + off);
    }
    // ---- B chunks: 224*32 elems = 896 x (8 bf16); thread t takes chunk t and t+512
    const s16x8 bv0 = *(const s16x8*)(Bt + (nb*224 + (t>>2))*KTOT + ks*32 + aq*8);
    s16x8 bv1 = zv;
    if (t < 384)
      bv1 = *(const s16x8*)(Bt + (nb*224 + 128 + (t>>2))*KTOT + ks*32 + aq*8);

    __syncthreads();   // previous iteration's frag reads done
    *(s16x8*)&Als[ar][aq*8] = av;
    *(s16x8*)&Bls[t>>2][aq*8] = bv0;
    if (t < 384) *(s16x8*)&Bls[128 + (t>>2)][aq*8] = bv1;
    __syncthreads();   // tiles ready

    const bf16x8 af0 = *(const bf16x8*)&Als[wm*32 +      lr][lg*8];
    const bf16x8 af1 = *(const bf16x8*)&Als[wm*32 + 16 + lr][lg*8];
#pragma unroll
    for (int ni=0; ni<7; ++ni) {
      const bf16x8 bfr = *(const bf16x8*)&Bls[wn*112 + ni*16 + lr][lg*8];
      acc[0][ni] = __builtin_amdgcn_mfma_f32_16x16x32_bf16(af0, bfr, acc[0][ni], 0,0,0);
      acc[1][ni] = __builtin_amdgcn_mfma_f32_16x16x32_bf16(af1, bfr, acc[1][ni], 0,0,0);
    }
  }

  // ---- epilogue ----
#pragma unroll
  for (int mi=0; mi<2; ++mi) {
    const int rbase = bm*128 + wm*32 + mi*16 + lg*4;
#pragma unroll
    for (int ni=0; ni<7; ++ni) {
      const int col = wn*112 + ni*16 + lr;
      const int n   = nb*224 + col;
      float badd = 0.f;
      if constexpr (MODE != M_QKV) badd = bias[n];
#pragma unroll
      for (int r=0;r<4;r++){
        const int prow = rbase + r;
        float v = acc[mi][ni][r] + badd;
        if constexpr (CONV) v = fmaxf(v, 0.f);
        if constexpr (MODE==M_C3) {
          v += bf2f(resid[prow*224 + col]);            // X2S = relu(conv3)+res
          ((float*)Dv)[prow*672 + 448 + col] = v;      // d_out channels 448..671 (f32)
        } else if constexpr (MODE==M_OUT) {
          ((float*)Dv)[prow*672 + n] = v;              // d_out channels 0..447 (f32)
        } else if constexpr (MODE==M_QKV) {
          ((u16*)Dv)[prow*672 + n] = f2bf(v);          // qkv (bf16 ws)
        } else {
          ((u16*)Dv)[prow*224 + col] = f2bf(v);        // conv intermediates (bf16 ws)
        }
      }
    }
  }
}

// ---------------------------------------------------------------------------
// Branch-1 attention: per (b, window n): 4 heads x 64 tokens, dh=28.
// Block = 256 thr (wave h), lane = query token m. K/V staged to LDS fp32,
// uniform-row broadcast reads. qkv layout [pix][672]: q|k|v each 224.
// ---------------------------------------------------------------------------
__global__ __launch_bounds__(256,2) void attn1_k(const u16* __restrict__ qkv,
    const float* __restrict__ pos1, u16* __restrict__ attnout)
{
  __shared__ __align__(16) float KL[64][112];
  __shared__ __align__(16) float VL[64][112];
  const int t = threadIdx.x;
  const int b = blockIdx.x>>4, n = blockIdx.x&15;
  const int base = b*1024 + (n>>2)*256 + (n&3)*8;     // pixel of (window n, m=0)
  // pix(m) = base + (m>>3)*32 + (m&7)
  {
    const int r = t>>2, part = t&3;
    const int pr_ = base + (r>>3)*32 + (r&7);
    const u16* kp = qkv + pr_*672 + 224 + part*28;    // k1 channels
    const u16* vp = kp + 224;                          // v1 channels
#pragma unroll
    for (int j=0;j<7;j++){
      u32x2 kk = *(const u32x2*)(kp + j*4);
      u32x2 vv = *(const u32x2*)(vp + j*4);
      const int c = part*28 + j*4;
      KL[r][c+0]=bf2f((u16)(kk[0]&0xffffu)); KL[r][c+1]=bf2f((u16)(kk[0]>>16));
      KL[r][c+2]=bf2f((u16)(kk[1]&0xffffu)); KL[r][c+3]=bf2f((u16)(kk[1]>>16));
      VL[r][c+0]=bf2f((u16)(vv[0]&0xffffu)); VL[r][c+1]=bf2f((u16)(vv[0]>>16));
      VL[r][c+2]=bf2f((u16)(vv[1]&0xffffu)); VL[r][c+3]=bf2f((u16)(vv[1]>>16));
    }
  }
  __syncthreads();

  const int h = t>>6, i = t&63;
  const int pi = base + (i>>3)*32 + (i&7);
  float q[28];
  ld28(qkv + pi*672 + h*28, q, SCALE_Q);

  float s[64];
  const float* pr = pos1 + (h*64+i)*64;               // pos_emb1 (f32)
#pragma unroll
  for (int j4=0;j4<16;j4++){
    f32x4 pv = *(const f32x4*)(pr + j4*4);
    s[j4*4+0]=pv[0]; s[j4*4+1]=pv[1]; s[j4*4+2]=pv[2]; s[j4*4+3]=pv[3];
  }
  const int c0 = h*28;
#pragma unroll
  for (int j=0;j<64;j++){
    const f32x4* kr = (const f32x4*)&KL[j][c0];
    float a0=0.f,a1=0.f,a2=0.f,a3=0.f;
#pragma unroll
    for (int u=0;u<7;u++){
      f32x4 kv = kr[u];
      a0 += q[u*4+0]*kv[0]; a1 += q[u*4+1]*kv[1];
      a2 += q[u*4+2]*kv[2]; a3 += q[u*4+3]*kv[3];
    }
    s[j] += (a0+a1)+(a2+a3);
  }
  float mx = s[0];
#pragma unroll
  for (int j=1;j<64;j++) mx = fmaxf(mx, s[j]);
  float sum = 0.f;
#pragma unroll
  for (int j=0;j<64;j++){ float e = __expf(s[j]-mx); s[j]=e; sum+=e; }
  const float inv = 1.f/sum;

  float out[28];
#pragma unroll
  for (int u=0;u<28;u++) out[u]=0.f;
#pragma unroll
  for (int j=0;j<64;j++){
    const float pj = s[j];
    const f32x4* vr = (const f32x4*)&VL[j][c0];
#pragma unroll
    for (int u=0;u<7;u++){
      f32x4 vv = vr[u];
      out[u*4+0] += pj*vv[0]; out[u*4+1] += pj*vv[1];
      out[u*4+2] += pj*vv[2]; out[u*4+3] += pj*vv[3];
    }
  }
  u16* op = attnout + pi*224 + h*28;                  // out1 -> cols 0..111
#pragma unroll
  for (int u=0;u<7;u++){
    u32x2 wv;
    wv[0] = (u32)f2bf(out[u*4+0]*inv) | ((u32)f2bf(out[u*4+1]*inv)<<16);
    wv[1] = (u32)f2bf(out[u*4+2]*inv) | ((u32)f2bf(out[u*4+3]*inv)<<16);
    *(u32x2*)(op + u*4) = wv;
  }
}

// ---------------------------------------------------------------------------
// Branch-2 attention: per (b, within-window pos m): 4 heads x 16 windows.
// Wave = one (b,m); lane: h = l>>4, i = l&15 (query window). L2-hot direct reads.
// ---------------------------------------------------------------------------
__global__ __launch_bounds__(256,1) void attn2_k(const u16* __restrict__ qkv,
    const float* __restrict__ pos2, u16* __restrict__ attnout)
{
  const int t = threadIdx.x;
  const int b = blockIdx.x>>4, mg = blockIdx.x&15;
  const int m = mg*4 + (t>>6);
  const int lane = t&63, h = lane>>4, i = lane&15;
  const int base = b*1024 + (m>>3)*32 + (m&7);
  // pix(n) = base + (n>>2)*256 + (n&3)*8
  const int pi = base + (i>>2)*256 + (i&3)*8;

  float q[28];
  ld28(qkv + pi*672 + 112 + h*28, q, SCALE_Q);        // q2 channels

  float s[16];
  const float* pr = pos2 + (h*16+i)*16;               // pos_emb2 (f32)
#pragma unroll
  for (int j4=0;j4<4;j4++){
    f32x4 pv = *(const f32x4*)(pr + j4*4);
    s[j4*4+0]=pv[0]; s[j4*4+1]=pv[1]; s[j4*4+2]=pv[2]; s[j4*4+3]=pv[3];
  }
#pragma unroll
  for (int j=0;j<16;j++){
    const int pj_ = base + (j>>2)*256 + (j&3)*8;
    float kk[28];
    ld28(qkv + pj_*672 + 336 + h*28, kk, 1.0f);       // k2 channels
    float a=0.f;
#pragma unroll
    for (int u=0;u<28;u++) a += q[u]*kk[u];
    s[j] += a;
  }
  float mx = s[0];
#pragma unroll
  for (int j=1;j<16;j++) mx = fmaxf(mx, s[j]);
  float sum = 0.f;
#pragma unroll
  for (int j=0;j<16;j++){ float e = __expf(s[j]-mx); s[j]=e; sum+=e; }
  const float inv = 1.f/sum;

  float out[28];
#pragma unroll
  for (int u=0;u<28;u++) out[u]=0.f;
#pragma unroll
  for (int j=0;j<16;j++){
    const int pj_ = base + (j>>2)*256 + (j&3)*8;
    float vv[28];
    ld28(qkv + pj_*672 + 560 + h*28, vv, 1.0f);       // v2 channels
    const float pj = s[j];
#pragma unroll
    for (int u=0;u<28;u++) out[u] += pj*vv[u];
  }
  u16* op = attnout + pi*224 + 112 + h*28;            // out2 -> cols 112..223
#pragma unroll
  for (int u=0;u<7;u++){
    u32x2 wv;
    wv[0] = (u32)f2bf(out[u*4+0]*inv) | ((u32)f2bf(out[u*4+1]*inv)<<16);
    wv[1] = (u32)f2bf(out[u*4+2]*inv) | ((u32)f2bf(out[u*4+3]*inv)<<16);
    *(u32x2*)(op + u*4) = wv;
  }
}

// ---------------------------------------------------------------------------
extern "C" void kernel_launch(void* const* d_in, const int* in_sizes, int n_in,
                              void* d_out, int out_size, void* d_ws, size_t ws_size,
                              hipStream_t stream) {
  const float* x    = (const float*)d_in[0];
  const float* pos1 = (const float*)d_in[1];
  const float* pos2 = (const float*)d_in[2];
  const float* Wq   = (const float*)d_in[3];
  const float* Wkv  = (const float*)d_in[4];
  const float* Wout = (const float*)d_in[5];
  const float* bout = (const float*)d_in[6];
  const float* wr   = (const float*)d_in[7];
  const float* br   = (const float*)d_in[8];
  const float* w1   = (const float*)d_in[9];
  const float* b1   = (const float*)d_in[10];
  const float* w2   = (const float*)d_in[11];
  const float* b2   = (const float*)d_in[12];
  const float* w3   = (const float*)d_in[13];
  const float* b3   = (const float*)d_in[14];

  char* ws = (char*)d_ws;
  const size_t SLOT = 65536ull*224*2;   // 29,360,128 B
  // phase 1 (convs): res/oA/oB ; phase 2: region reused as qkv [65536][672]
  u16* res  = (u16*)(ws);
  u16* oA   = (u16*)(ws + SLOT);
  u16* oB   = (u16*)(ws + 2*SLOT);
  u16* qkv  = (u16*)(ws);
  u16* attnout = (u16*)(ws + 3*SLOT);
  u16* WqkvT   = (u16*)(ws + 4*SLOT);
  u16* WoutT   = WqkvT + 672*224;
  u16* convW   = WoutT + 448*224;       // [4][224][2016]
  float* dout  = (float*)d_out;

  pack_k<<<8036, 256, 0, stream>>>(Wq, Wkv, Wout, wr, w1, w2, w3, WqkvT, WoutT, convW);

  // conv phase (writes d_out channels 448..671 at the end)
  gemm_k<M_CX2><<<dim3(512,1), 512, 0, stream>>>(x,  convW + 0*451584, br, nullptr, res);
  gemm_k<M_CX2><<<dim3(512,1), 512, 0, stream>>>(x,  convW + 1*451584, b1, nullptr, oA);
  gemm_k<M_CBF><<<dim3(512,1), 512, 0, stream>>>(oA, convW + 2*451584, b2, nullptr, oB);
  gemm_k<M_C3 ><<<dim3(512,1), 512, 0, stream>>>(oB, convW + 3*451584, b3, res, dout);

  // attention phase (reuses conv buffer region for qkv)
  gemm_k<M_QKV><<<dim3(512,3), 512, 0, stream>>>(x, WqkvT, nullptr, nullptr, qkv);
  attn1_k<<<1024, 256, 0, stream>>>(qkv, pos1, attnout);
  attn2_k<<<1024, 256, 0, stream>>>(qkv, pos2, attnout);
  gemm_k<M_OUT><<<dim3(512,2), 512, 0, stream>>>(attnout, WoutT, bout, nullptr, dout);
}